// Round 10
// baseline (2071.634 us; speedup 1.0000x reference)
//
#include <hip/hip_runtime.h>
#include <hip/hip_fp16.h>
#include <math.h>

#define HID 64
#define NLAYERS 8
#define NTH 512        // 8 waves/block; 4 blocks/CU (LDS 32KB) -> 32 waves/CU
#define PRE_NTH 256
#define SF 4           // 16-sample fragments per wave => 64 samples/wave

// LDS slot blob = A2|A3 only: 8192 ushort = 16384 B = exactly 2 stage rounds
#define SLOT_US 8192
#define A2_US 0
#define A3_US 4096
// ws float-unit offsets
#define WS_A1T_F  65536                 // blobs: [0,65536) floats (16 x 8192 us)
#define WS_A4_F   67584                 // A1T: 16 x 64 lanes x 4 us = [65536,67584)
#define WS_BIAS_F 75776                 // A4: 16 x 2ks x 64 x 8 us = [67584,75776)
#define WS_B4_F   124928                // biases: 16 x 3072 floats
// ushort-unit mirrors
#define A1T_US (WS_A1T_F * 2)
#define A4_USO (WS_A4_F * 2)

typedef __attribute__((ext_vector_type(8))) _Float16 f16x8;
typedef __attribute__((ext_vector_type(2))) _Float16 f16x2;
typedef __attribute__((ext_vector_type(4))) float f32x4;

__device__ __forceinline__ unsigned short f2h(float f) {
    return __builtin_bit_cast(unsigned short, (_Float16)f);  // RNE scalar cvt
}

// f32 pair -> packed f16 (RTZ), one v_cvt_pkrtz_f16_f32
__device__ __forceinline__ f16x2 cvt2(float a, float b) {
    auto r = __builtin_amdgcn_cvt_pkrtz(a, b);
    return __builtin_bit_cast(f16x2, r);
}

// packed ReLU: one v_pk_max_f16 (relu∘cvt == cvt∘relu)
__device__ __forceinline__ f16x2 relu2(f16x2 x) {
    const f16x2 z = {(_Float16)0.f, (_Float16)0.f};
    return __builtin_elementwise_max(x, z);
}

// relu + f32->f16 pack: 8 VALU ops per 8 elems
__device__ __forceinline__ f16x8 packR(f32x4 a, f32x4 b) {
    union { f16x2 h[4]; f16x8 v; } o;
    o.h[0] = relu2(cvt2(a[0], a[1]));
    o.h[1] = relu2(cvt2(a[2], a[3]));
    o.h[2] = relu2(cvt2(b[0], b[1]));
    o.h[3] = relu2(cvt2(b[2], b[3]));
    return o.v;
}

// build {val,0,0,0,0,0,0,0} A1 fragment from a 16-bit payload
__device__ __forceinline__ f16x8 a1frag(unsigned int val16) {
    union { unsigned int u[4]; f16x8 v; } b;
    b.u[0] = val16; b.u[1] = 0u; b.u[2] = 0u; b.u[3] = 0u;
    return b.v;
}

// DMA one 16B chunk per lane: global -> LDS (wave-uniform LDS base + lane*16).
__device__ __forceinline__ void gload16(const unsigned short* g, unsigned short* l) {
    __builtin_amdgcn_global_load_lds(
        (const __attribute__((address_space(1))) unsigned int*)g,
        (__attribute__((address_space(3))) unsigned int*)l, 16, 0, 0);
}

// Stage one 16384B slot blob: 8 waves x 2 rounds x 64 lanes x 16B (exact).
__device__ __forceinline__ void stage(unsigned short* lds, const unsigned short* gsrc, int tid) {
    const int lane = tid & 63, wv = tid >> 6;
#pragma unroll
    for (int r = 0; r < 2; ++r) {
        const int chunk = r * 512 + wv * 64;             // in 16B units
        gload16(gsrc + (chunk + lane) * 8, lds + chunk * 8);
    }
}

// One block per (layer, net) slot. A-frag K-permutation
// k(ks,g,e)=16*(2ks+(e>>2))+4g+(e&3) makes layer n's D-layout directly
// consumable as layer n+1's B-operand. Weights stored as f16 bits.
__global__ void prepack_kernel(
    const float* __restrict__ s_w1, const float* __restrict__ s_b1,
    const float* __restrict__ s_w2, const float* __restrict__ s_b2,
    const float* __restrict__ s_w3, const float* __restrict__ s_b3,
    const float* __restrict__ s_w4, const float* __restrict__ s_b4,
    const float* __restrict__ t_w1, const float* __restrict__ t_b1,
    const float* __restrict__ t_w2, const float* __restrict__ t_b2,
    const float* __restrict__ t_w3, const float* __restrict__ t_b3,
    const float* __restrict__ t_w4, const float* __restrict__ t_b4,
    float* __restrict__ ws) {
    const int slot = blockIdx.x;            // l*2 + net
    const int l = slot >> 1, net = slot & 1;
    const int act = l & 1, pass = act ^ 1;
    const float* w1 = (net ? t_w1 : s_w1) + l * HID * 2;
    const float* b1 = (net ? t_b1 : s_b1) + l * HID;
    const float* w2 = (net ? t_w2 : s_w2) + l * HID * HID;
    const float* b2 = (net ? t_b2 : s_b2) + l * HID;
    const float* w3 = (net ? t_w3 : s_w3) + l * HID * HID;
    const float* b3 = (net ? t_b3 : s_b3) + l * HID;
    const float* w4 = (net ? t_w4 : s_w4) + l * 2 * HID;
    const float* b4 = (net ? t_b4 : s_b4) + l * 2;

    unsigned short* wsu = reinterpret_cast<unsigned short*>(ws);
    unsigned short* blob = wsu + slot * SLOT_US;

    // A2 / A3: 64x64 matmul fragments (LDS-staged at runtime)
    for (int mat = 0; mat < 2; ++mat) {
        const float* W = mat ? w3 : w2;
        unsigned short* dst = blob + (mat ? A3_US : A2_US);
        for (int idx = threadIdx.x; idx < 4096; idx += PRE_NTH) {
            const int e = idx & 7, lane = (idx >> 3) & 63, fr = idx >> 9;
            const int ks = fr & 1, mf = fr >> 1;
            const int j = 16 * mf + (lane & 15);
            const int k = 16 * (2 * ks + (e >> 2)) + 4 * (lane >> 4) + (e & 3);
            dst[idx] = f2h(W[j * HID + k]);
        }
    }
    // A1T: compact rank-1 layer-1 record, 4 ushort per lane (mf=0..3).
    // Value w1/4 at k=4g for every lane-group: every lane injects xa at elem 0.
    for (int idx = threadIdx.x; idx < 256; idx += PRE_NTH) {
        const int mf = idx & 3, lane = idx >> 2;
        const int j = 16 * mf + (lane & 15);
        wsu[A1T_US + (slot * 64 + lane) * 4 + mf] = f2h(w1[2 * j + act] * 0.25f);
    }
    // A4: W4 passive row in A row 0, rows 1..15 zero (global, fragment form)
    for (int idx = threadIdx.x; idx < 1024; idx += PRE_NTH) {
        const int e = idx & 7, lane = (idx >> 3) & 63, ks = idx >> 9;
        const int k = 16 * (2 * ks + (e >> 2)) + 4 * (lane >> 4) + (e & 3);
        wsu[A4_USO + (slot * 128 + ks * 64 + lane) * 8 + e] =
            f2h(((lane & 15) == 0) ? w4[pass * HID + k] : 0.f);
    }
    // biases b1,b2,b3 in D-fragment order (f32), kept in global (small)
    float* BP = ws + WS_BIAS_F + slot * 3072;
    for (int which = 0; which < 3; ++which) {
        const float* B = (which == 0) ? b1 : (which == 1) ? b2 : b3;
        for (int idx = threadIdx.x; idx < 1024; idx += PRE_NTH) {
            const int r = idx & 3, lane = (idx >> 2) & 63, f = idx >> 8;
            const int j = 16 * f + 4 * (lane >> 4) + r;
            BP[which * 1024 + idx] = B[j];
        }
    }
    if (threadIdx.x == 0) ws[WS_B4_F + slot] = b4[pass];
}

__global__ __launch_bounds__(NTH, 8) void nvp_mfma_kernel(
    const float* __restrict__ x, const float* __restrict__ ws,
    float* __restrict__ out, int n) {
    __shared__ __align__(16) unsigned short smem[2 * SLOT_US];  // 32 KB double buffer
    const int tid = threadIdx.x;
    const int lane = tid & 63, wv = tid >> 6;
    const int c = lane & 15, g = lane >> 4;
    const int wid = blockIdx.x * (NTH / 64) + wv;
    long base = (long)wid * (16 * SF);
    const bool live = base < n;
    if (!live) base = 0;   // keep barrier participation uniform; skip writes later

    const unsigned short* wsu = reinterpret_cast<const unsigned short*>(ws);

    float y0[SF], y1[SF], ld[SF];
#pragma unroll
    for (int sf = 0; sf < SF; ++sf) {
        const float2 xv = reinterpret_cast<const float2*>(x)[base + 16 * sf + c];
        y0[sf] = xv.x; y1[sf] = xv.y; ld[sf] = 0.f;
    }

    // prologue: stage slot 0
    stage(smem, wsu, tid);

    float sv[SF], tv[SF];
    _Float16 xs[SF];

    for (int slot = 0; slot < 2 * NLAYERS; ++slot) {
        const int net = slot & 1;
        const int act = (slot >> 1) & 1;

        // staged data for this slot is ready after this barrier (vmcnt drained);
        // also closes all waves' reads of the buffer we stage into below.
        __syncthreads();
        if (slot < 2 * NLAYERS - 1)
            stage(smem + ((slot + 1) & 1) * SLOT_US, wsu + (slot + 1) * SLOT_US, tid);

        const unsigned short* SB = smem + (slot & 1) * SLOT_US;
        const float* BP = ws + WS_BIAS_F + slot * 3072;

        if (net == 0) {   // both nets consume the same active input (RNE cast)
#pragma unroll
            for (int sf = 0; sf < SF; ++sf) {
                const float xa = act ? y1[sf] : y0[sf];
                xs[sf] = (_Float16)xa;
            }
        }

        // ---- phase A weights: A1 (global, compact), b1, b2 (global), A2 (LDS) ----
        const uint2 a1w = *reinterpret_cast<const uint2*>(wsu + A1T_US + (slot * 64 + lane) * 4);
        f16x8 a1[4];
        a1[0] = a1frag(a1w.x & 0xffffu);
        a1[1] = a1frag(a1w.x >> 16);
        a1[2] = a1frag(a1w.y & 0xffffu);
        a1[3] = a1frag(a1w.y >> 16);
        f16x8 a2[8];
        f32x4 c1v[4], c2v[4];
#pragma unroll
        for (int mf = 0; mf < 4; ++mf) {
            c1v[mf] = *reinterpret_cast<const f32x4*>(BP + 0 * 1024 + (mf * 64 + lane) * 4);
            c2v[mf] = *reinterpret_cast<const f32x4*>(BP + 1 * 1024 + (mf * 64 + lane) * 4);
        }
#pragma unroll
        for (int fr = 0; fr < 8; ++fr)
            a2[fr] = *reinterpret_cast<const f16x8*>(SB + A2_US + (fr * 64 + lane) * 8);

        f16x8 bfr[SF][2];
#pragma unroll
        for (int sf = 0; sf < SF; ++sf) {
            // B1 frag: f16(xa) at element 0 in ALL lanes (A1 holds w1/4 at k=4g)
            f16x8 b1f = {0, 0, 0, 0, 0, 0, 0, 0};
            b1f[0] = xs[sf];
            f32x4 acc[4];
            // layer 1: rank-1 MFMA, bias as C-in
#pragma unroll
            for (int mf = 0; mf < 4; ++mf)
                acc[mf] = __builtin_amdgcn_mfma_f32_16x16x32_f16(a1[mf], b1f, c1v[mf], 0, 0, 0);
            f16x8 bb0 = packR(acc[0], acc[1]);
            f16x8 bb1 = packR(acc[2], acc[3]);
            // layer 2
#pragma unroll
            for (int mf = 0; mf < 4; ++mf) {
                f32x4 t0 = __builtin_amdgcn_mfma_f32_16x16x32_f16(a2[2 * mf + 0], bb0, c2v[mf], 0, 0, 0);
                acc[mf]  = __builtin_amdgcn_mfma_f32_16x16x32_f16(a2[2 * mf + 1], bb1, t0, 0, 0, 0);
            }
            bfr[sf][0] = packR(acc[0], acc[1]);
            bfr[sf][1] = packR(acc[2], acc[3]);
        }

        // ---- phase B weights: A3 (LDS), b3 (global), A4 (global), b4 ----
        f16x8 a3[8], a4[2];
        f32x4 c3v[4];
#pragma unroll
        for (int fr = 0; fr < 8; ++fr)
            a3[fr] = *reinterpret_cast<const f16x8*>(SB + A3_US + (fr * 64 + lane) * 8);
#pragma unroll
        for (int mf = 0; mf < 4; ++mf)
            c3v[mf] = *reinterpret_cast<const f32x4*>(BP + 2 * 1024 + (mf * 64 + lane) * 4);
        a4[0] = *reinterpret_cast<const f16x8*>(wsu + A4_USO + (slot * 128 + 0 * 64 + lane) * 8);
        a4[1] = *reinterpret_cast<const f16x8*>(wsu + A4_USO + (slot * 128 + 1 * 64 + lane) * 8);
        const float b4v = ws[WS_B4_F + slot];

#pragma unroll
        for (int sf = 0; sf < SF; ++sf) {
            f32x4 acc[4];
            // layer 3
#pragma unroll
            for (int mf = 0; mf < 4; ++mf) {
                f32x4 t0 = __builtin_amdgcn_mfma_f32_16x16x32_f16(a3[2 * mf + 0], bfr[sf][0], c3v[mf], 0, 0, 0);
                acc[mf]  = __builtin_amdgcn_mfma_f32_16x16x32_f16(a3[2 * mf + 1], bfr[sf][1], t0, 0, 0, 0);
            }
            f16x8 bb0 = packR(acc[0], acc[1]);
            f16x8 bb1 = packR(acc[2], acc[3]);
            // layer 4: W4 row dot via MFMA row 0, then broadcast from lane c
            f32x4 z = {0.f, 0.f, 0.f, 0.f};
            f32x4 d4 = __builtin_amdgcn_mfma_f32_16x16x32_f16(a4[0], bb0, z, 0, 0, 0);
            d4 = __builtin_amdgcn_mfma_f32_16x16x32_f16(a4[1], bb1, d4, 0, 0, 0);
            float p = __builtin_bit_cast(float,
                        __builtin_amdgcn_ds_bpermute(c * 4, __builtin_bit_cast(int, d4[0])));
            p += b4v;
            if (net == 0) sv[sf] = p; else tv[sf] = p;
        }

        if (net == 1) {   // coupling update after both nets done
#pragma unroll
            for (int sf = 0; sf < SF; ++sf) {
                const float e2 = __expf(2.f * sv[sf]);
                const float s = 1.f - 2.f / (e2 + 1.f);      // tanh(sv)
                const float es = __expf(s);
                if (act) y0[sf] = fmaf(y0[sf], es, tv[sf]);
                else     y1[sf] = fmaf(y1[sf], es, tv[sf]);
                ld[sf] += s;
            }
        }
    }

    if (g == 0 && live) {   // 4 lane-groups hold identical results; group 0 writes
#pragma unroll
        for (int sf = 0; sf < SF; ++sf) {
            const long sid = base + 16 * sf + c;
            reinterpret_cast<float2*>(out)[sid] = make_float2(y0[sf], y1[sf]);
            out[2 * (long)n + sid] = ld[sf];
        }
    }
}

extern "C" void kernel_launch(void* const* d_in, const int* in_sizes, int n_in,
                              void* d_out, int out_size, void* d_ws, size_t ws_size,
                              hipStream_t stream) {
    const float* x = (const float*)d_in[0];
    float* ws = (float*)d_ws;

    prepack_kernel<<<16, PRE_NTH, 0, stream>>>(
        (const float*)d_in[1],  (const float*)d_in[2],  (const float*)d_in[3],
        (const float*)d_in[4],  (const float*)d_in[5],  (const float*)d_in[6],
        (const float*)d_in[7],  (const float*)d_in[8],  (const float*)d_in[9],
        (const float*)d_in[10], (const float*)d_in[11], (const float*)d_in[12],
        (const float*)d_in[13], (const float*)d_in[14], (const float*)d_in[15],
        (const float*)d_in[16], ws);

    const int n = in_sizes[0] / 2;                        // x is (N, 2)
    const int samples_per_block = (NTH / 64) * 16 * SF;   // 512
    const int blocks = (n + samples_per_block - 1) / samples_per_block;

    nvp_mfma_kernel<<<blocks, NTH, 0, stream>>>(x, ws, (float*)d_out, n);
}

// Round 11
// 1461.942 us; speedup vs baseline: 1.4170x; 1.4170x over previous
//
#include <hip/hip_runtime.h>
#include <hip/hip_fp16.h>
#include <math.h>

#define HID 64
#define NLAYERS 8
#define NTH 256        // 4 waves/block; LDS 32KB -> 5 blocks/CU = 20 waves/CU
#define PRE_NTH 256
#define SF 4           // 16-sample fragments per wave => 64 samples/wave

// LDS slot blob = A2|A3 only: 8192 ushort = 16384 B
#define SLOT_US 8192
#define A2_US 0
#define A3_US 4096
// ws float-unit offsets
#define WS_A1T_F  65536                 // blobs: [0,65536) floats (16 x 8192 us)
#define WS_A4_F   67584                 // A1T: 16 x 64 lanes x 4 us = [65536,67584)
#define WS_BIAS_F 75776                 // A4: 16 x 2ks x 64 x 8 us = [67584,75776)
#define WS_B4_F   124928                // biases: 16 x 3072 floats
// ushort-unit mirrors
#define A1T_US (WS_A1T_F * 2)
#define A4_USO (WS_A4_F * 2)

typedef __attribute__((ext_vector_type(8))) _Float16 f16x8;
typedef __attribute__((ext_vector_type(2))) _Float16 f16x2;
typedef __attribute__((ext_vector_type(4))) float f32x4;

__device__ __forceinline__ unsigned short f2h(float f) {
    return __builtin_bit_cast(unsigned short, (_Float16)f);  // RNE scalar cvt
}

// f32 pair -> packed f16 (RTZ), one v_cvt_pkrtz_f16_f32
__device__ __forceinline__ f16x2 cvt2(float a, float b) {
    auto r = __builtin_amdgcn_cvt_pkrtz(a, b);
    return __builtin_bit_cast(f16x2, r);
}

// packed ReLU: one v_pk_max_f16 (relu∘cvt == cvt∘relu)
__device__ __forceinline__ f16x2 relu2(f16x2 x) {
    const f16x2 z = {(_Float16)0.f, (_Float16)0.f};
    return __builtin_elementwise_max(x, z);
}

// relu + f32->f16 pack: 8 VALU ops per 8 elems
__device__ __forceinline__ f16x8 packR(f32x4 a, f32x4 b) {
    union { f16x2 h[4]; f16x8 v; } o;
    o.h[0] = relu2(cvt2(a[0], a[1]));
    o.h[1] = relu2(cvt2(a[2], a[3]));
    o.h[2] = relu2(cvt2(b[0], b[1]));
    o.h[3] = relu2(cvt2(b[2], b[3]));
    return o.v;
}

// build {val,0,0,0,0,0,0,0} A1 fragment from a 16-bit payload
__device__ __forceinline__ f16x8 a1frag(unsigned int val16) {
    union { unsigned int u[4]; f16x8 v; } b;
    b.u[0] = val16; b.u[1] = 0u; b.u[2] = 0u; b.u[3] = 0u;
    return b.v;
}

// DMA one 16B chunk per lane: global -> LDS (wave-uniform LDS base + lane*16).
__device__ __forceinline__ void gload16(const unsigned short* g, unsigned short* l) {
    __builtin_amdgcn_global_load_lds(
        (const __attribute__((address_space(1))) unsigned int*)g,
        (__attribute__((address_space(3))) unsigned int*)l, 16, 0, 0);
}

// Stage one 16384B slot blob: 4 waves x 4 rounds x 64 lanes x 16B (exact).
__device__ __forceinline__ void stage(unsigned short* lds, const unsigned short* gsrc, int tid) {
    const int lane = tid & 63, wv = tid >> 6;
#pragma unroll
    for (int r = 0; r < 4; ++r) {
        const int chunk = r * 256 + wv * 64;             // in 16B units
        gload16(gsrc + (chunk + lane) * 8, lds + chunk * 8);
    }
}

// One block per (layer, net) slot. A-frag K-permutation
// k(ks,g,e)=16*(2ks+(e>>2))+4g+(e&3) makes layer n's D-layout directly
// consumable as layer n+1's B-operand. Weights stored as f16 bits.
__global__ void prepack_kernel(
    const float* __restrict__ s_w1, const float* __restrict__ s_b1,
    const float* __restrict__ s_w2, const float* __restrict__ s_b2,
    const float* __restrict__ s_w3, const float* __restrict__ s_b3,
    const float* __restrict__ s_w4, const float* __restrict__ s_b4,
    const float* __restrict__ t_w1, const float* __restrict__ t_b1,
    const float* __restrict__ t_w2, const float* __restrict__ t_b2,
    const float* __restrict__ t_w3, const float* __restrict__ t_b3,
    const float* __restrict__ t_w4, const float* __restrict__ t_b4,
    float* __restrict__ ws) {
    const int slot = blockIdx.x;            // l*2 + net
    const int l = slot >> 1, net = slot & 1;
    const int act = l & 1, pass = act ^ 1;
    const float* w1 = (net ? t_w1 : s_w1) + l * HID * 2;
    const float* b1 = (net ? t_b1 : s_b1) + l * HID;
    const float* w2 = (net ? t_w2 : s_w2) + l * HID * HID;
    const float* b2 = (net ? t_b2 : s_b2) + l * HID;
    const float* w3 = (net ? t_w3 : s_w3) + l * HID * HID;
    const float* b3 = (net ? t_b3 : s_b3) + l * HID;
    const float* w4 = (net ? t_w4 : s_w4) + l * 2 * HID;
    const float* b4 = (net ? t_b4 : s_b4) + l * 2;

    unsigned short* wsu = reinterpret_cast<unsigned short*>(ws);
    unsigned short* blob = wsu + slot * SLOT_US;

    // A2 / A3: 64x64 matmul fragments (LDS-staged at runtime)
    for (int mat = 0; mat < 2; ++mat) {
        const float* W = mat ? w3 : w2;
        unsigned short* dst = blob + (mat ? A3_US : A2_US);
        for (int idx = threadIdx.x; idx < 4096; idx += PRE_NTH) {
            const int e = idx & 7, lane = (idx >> 3) & 63, fr = idx >> 9;
            const int ks = fr & 1, mf = fr >> 1;
            const int j = 16 * mf + (lane & 15);
            const int k = 16 * (2 * ks + (e >> 2)) + 4 * (lane >> 4) + (e & 3);
            dst[idx] = f2h(W[j * HID + k]);
        }
    }
    // A1T: compact rank-1 layer-1 record, 4 ushort per lane (mf=0..3).
    // Value w1/4 at k=4g for every lane-group: every lane injects xa at elem 0.
    for (int idx = threadIdx.x; idx < 256; idx += PRE_NTH) {
        const int mf = idx & 3, lane = idx >> 2;
        const int j = 16 * mf + (lane & 15);
        wsu[A1T_US + (slot * 64 + lane) * 4 + mf] = f2h(w1[2 * j + act] * 0.25f);
    }
    // A4: W4 passive row in A row 0, rows 1..15 zero (global, fragment form)
    for (int idx = threadIdx.x; idx < 1024; idx += PRE_NTH) {
        const int e = idx & 7, lane = (idx >> 3) & 63, ks = idx >> 9;
        const int k = 16 * (2 * ks + (e >> 2)) + 4 * (lane >> 4) + (e & 3);
        wsu[A4_USO + (slot * 128 + ks * 64 + lane) * 8 + e] =
            f2h(((lane & 15) == 0) ? w4[pass * HID + k] : 0.f);
    }
    // biases b1,b2,b3 in D-fragment order (f32), kept in global (small)
    float* BP = ws + WS_BIAS_F + slot * 3072;
    for (int which = 0; which < 3; ++which) {
        const float* B = (which == 0) ? b1 : (which == 1) ? b2 : b3;
        for (int idx = threadIdx.x; idx < 1024; idx += PRE_NTH) {
            const int r = idx & 3, lane = (idx >> 2) & 63, f = idx >> 8;
            const int j = 16 * f + 4 * (lane >> 4) + r;
            BP[which * 1024 + idx] = B[j];
        }
    }
    if (threadIdx.x == 0) ws[WS_B4_F + slot] = b4[pass];
}

// 5 waves/EU target -> VGPR cap 102 (SF=4 demand ~90; r10 lesson: cap 64 spilled)
__global__ __launch_bounds__(NTH, 5) void nvp_mfma_kernel(
    const float* __restrict__ x, const float* __restrict__ ws,
    float* __restrict__ out, int n) {
    __shared__ __align__(16) unsigned short smem[2 * SLOT_US];  // 32 KB double buffer
    const int tid = threadIdx.x;
    const int lane = tid & 63, wv = tid >> 6;
    const int c = lane & 15, g = lane >> 4;
    const int wid = blockIdx.x * (NTH / 64) + wv;
    long base = (long)wid * (16 * SF);
    const bool live = base < n;
    if (!live) base = 0;   // keep barrier participation uniform; skip writes later

    const unsigned short* wsu = reinterpret_cast<const unsigned short*>(ws);

    float y0[SF], y1[SF], ld[SF];
#pragma unroll
    for (int sf = 0; sf < SF; ++sf) {
        const float2 xv = reinterpret_cast<const float2*>(x)[base + 16 * sf + c];
        y0[sf] = xv.x; y1[sf] = xv.y; ld[sf] = 0.f;
    }

    // prologue: stage slot 0
    stage(smem, wsu, tid);

    float sv[SF], tv[SF];
    _Float16 xs[SF];

    for (int slot = 0; slot < 2 * NLAYERS; ++slot) {
        const int net = slot & 1;
        const int act = (slot >> 1) & 1;

        // staged data for this slot is ready after this barrier (vmcnt drained);
        // also closes all waves' reads of the buffer we stage into below.
        __syncthreads();
        if (slot < 2 * NLAYERS - 1)
            stage(smem + ((slot + 1) & 1) * SLOT_US, wsu + (slot + 1) * SLOT_US, tid);

        const unsigned short* SB = smem + (slot & 1) * SLOT_US;
        const float* BP = ws + WS_BIAS_F + slot * 3072;

        if (net == 0) {   // both nets consume the same active input (RNE cast)
#pragma unroll
            for (int sf = 0; sf < SF; ++sf) {
                const float xa = act ? y1[sf] : y0[sf];
                xs[sf] = (_Float16)xa;
            }
        }

        // ---- phase A weights: A1 (global, compact), b1, b2 (global), A2 (LDS) ----
        const uint2 a1w = *reinterpret_cast<const uint2*>(wsu + A1T_US + (slot * 64 + lane) * 4);
        f16x8 a1[4];
        a1[0] = a1frag(a1w.x & 0xffffu);
        a1[1] = a1frag(a1w.x >> 16);
        a1[2] = a1frag(a1w.y & 0xffffu);
        a1[3] = a1frag(a1w.y >> 16);
        f16x8 a2[8];
        f32x4 c1v[4], c2v[4];
#pragma unroll
        for (int mf = 0; mf < 4; ++mf) {
            c1v[mf] = *reinterpret_cast<const f32x4*>(BP + 0 * 1024 + (mf * 64 + lane) * 4);
            c2v[mf] = *reinterpret_cast<const f32x4*>(BP + 1 * 1024 + (mf * 64 + lane) * 4);
        }
#pragma unroll
        for (int fr = 0; fr < 8; ++fr)
            a2[fr] = *reinterpret_cast<const f16x8*>(SB + A2_US + (fr * 64 + lane) * 8);

        f16x8 bfr[SF][2];
#pragma unroll
        for (int sf = 0; sf < SF; ++sf) {
            // B1 frag: f16(xa) at element 0 in ALL lanes (A1 holds w1/4 at k=4g)
            f16x8 b1f = {0, 0, 0, 0, 0, 0, 0, 0};
            b1f[0] = xs[sf];
            f32x4 acc[4];
            // layer 1: rank-1 MFMA, bias as C-in
#pragma unroll
            for (int mf = 0; mf < 4; ++mf)
                acc[mf] = __builtin_amdgcn_mfma_f32_16x16x32_f16(a1[mf], b1f, c1v[mf], 0, 0, 0);
            f16x8 bb0 = packR(acc[0], acc[1]);
            f16x8 bb1 = packR(acc[2], acc[3]);
            // layer 2
#pragma unroll
            for (int mf = 0; mf < 4; ++mf) {
                f32x4 t0 = __builtin_amdgcn_mfma_f32_16x16x32_f16(a2[2 * mf + 0], bb0, c2v[mf], 0, 0, 0);
                acc[mf]  = __builtin_amdgcn_mfma_f32_16x16x32_f16(a2[2 * mf + 1], bb1, t0, 0, 0, 0);
            }
            bfr[sf][0] = packR(acc[0], acc[1]);
            bfr[sf][1] = packR(acc[2], acc[3]);
        }

        // ---- phase B weights: A3 (LDS), b3 (global), A4 (global), b4 ----
        f16x8 a3[8], a4[2];
        f32x4 c3v[4];
#pragma unroll
        for (int fr = 0; fr < 8; ++fr)
            a3[fr] = *reinterpret_cast<const f16x8*>(SB + A3_US + (fr * 64 + lane) * 8);
#pragma unroll
        for (int mf = 0; mf < 4; ++mf)
            c3v[mf] = *reinterpret_cast<const f32x4*>(BP + 2 * 1024 + (mf * 64 + lane) * 4);
        a4[0] = *reinterpret_cast<const f16x8*>(wsu + A4_USO + (slot * 128 + 0 * 64 + lane) * 8);
        a4[1] = *reinterpret_cast<const f16x8*>(wsu + A4_USO + (slot * 128 + 1 * 64 + lane) * 8);
        const float b4v = ws[WS_B4_F + slot];

#pragma unroll
        for (int sf = 0; sf < SF; ++sf) {
            f32x4 acc[4];
            // layer 3
#pragma unroll
            for (int mf = 0; mf < 4; ++mf) {
                f32x4 t0 = __builtin_amdgcn_mfma_f32_16x16x32_f16(a3[2 * mf + 0], bfr[sf][0], c3v[mf], 0, 0, 0);
                acc[mf]  = __builtin_amdgcn_mfma_f32_16x16x32_f16(a3[2 * mf + 1], bfr[sf][1], t0, 0, 0, 0);
            }
            f16x8 bb0 = packR(acc[0], acc[1]);
            f16x8 bb1 = packR(acc[2], acc[3]);
            // layer 4: W4 row dot via MFMA row 0, then broadcast from lane c
            f32x4 z = {0.f, 0.f, 0.f, 0.f};
            f32x4 d4 = __builtin_amdgcn_mfma_f32_16x16x32_f16(a4[0], bb0, z, 0, 0, 0);
            d4 = __builtin_amdgcn_mfma_f32_16x16x32_f16(a4[1], bb1, d4, 0, 0, 0);
            float p = __builtin_bit_cast(float,
                        __builtin_amdgcn_ds_bpermute(c * 4, __builtin_bit_cast(int, d4[0])));
            p += b4v;
            if (net == 0) sv[sf] = p; else tv[sf] = p;
        }

        if (net == 1) {   // coupling update after both nets done
#pragma unroll
            for (int sf = 0; sf < SF; ++sf) {
                const float e2 = __expf(2.f * sv[sf]);
                const float s = 1.f - 2.f / (e2 + 1.f);      // tanh(sv)
                const float es = __expf(s);
                if (act) y0[sf] = fmaf(y0[sf], es, tv[sf]);
                else     y1[sf] = fmaf(y1[sf], es, tv[sf]);
                ld[sf] += s;
            }
        }
    }

    if (g == 0 && live) {   // 4 lane-groups hold identical results; group 0 writes
#pragma unroll
        for (int sf = 0; sf < SF; ++sf) {
            const long sid = base + 16 * sf + c;
            reinterpret_cast<float2*>(out)[sid] = make_float2(y0[sf], y1[sf]);
            out[2 * (long)n + sid] = ld[sf];
        }
    }
}

extern "C" void kernel_launch(void* const* d_in, const int* in_sizes, int n_in,
                              void* d_out, int out_size, void* d_ws, size_t ws_size,
                              hipStream_t stream) {
    const float* x = (const float*)d_in[0];
    float* ws = (float*)d_ws;

    prepack_kernel<<<16, PRE_NTH, 0, stream>>>(
        (const float*)d_in[1],  (const float*)d_in[2],  (const float*)d_in[3],
        (const float*)d_in[4],  (const float*)d_in[5],  (const float*)d_in[6],
        (const float*)d_in[7],  (const float*)d_in[8],  (const float*)d_in[9],
        (const float*)d_in[10], (const float*)d_in[11], (const float*)d_in[12],
        (const float*)d_in[13], (const float*)d_in[14], (const float*)d_in[15],
        (const float*)d_in[16], ws);

    const int n = in_sizes[0] / 2;                        // x is (N, 2)
    const int samples_per_block = (NTH / 64) * 16 * SF;   // 256
    const int blocks = (n + samples_per_block - 1) / samples_per_block;

    nvp_mfma_kernel<<<blocks, NTH, 0, stream>>>(x, ws, (float*)d_out, n);
}

// Round 12
// 160.404 us; speedup vs baseline: 12.9151x; 9.1141x over previous
//
#include <hip/hip_runtime.h>
#include <hip/hip_fp16.h>
#include <math.h>

#define HID 64
#define NLAYERS 8
#define NTH 256        // 4 waves/block; 4 independent blocks/CU -> phase diversity
#define PRE_NTH 256
#define SF 8           // 16-sample fragments per wave => 128 samples/wave

// LDS slot blob = A2|A3 only: 8192 ushort = 16384 B
#define SLOT_US 8192
#define A2_US 0
#define A3_US 4096
// ws ushort-unit offsets
#define W1T_US 131072                 // blobs: [0,131072) us
#define B1T_US (W1T_US + 16384)      // w1 lane-tables: 16 slots x 64 x 16 us
#define A4_USO (B1T_US + 16384)      // b1 lane-tables
// ws float-unit offsets
#define WS_BIAS_F ((A4_USO + 16384) / 2)   // A4 frags: 16 x 2 x 64 x 8 us
#define WS_B4_F   (WS_BIAS_F + 16 * 2048)  // b2,b3 f32 frags per slot

typedef __attribute__((ext_vector_type(8))) _Float16 f16x8;
typedef __attribute__((ext_vector_type(2))) _Float16 f16x2;
typedef __attribute__((ext_vector_type(4))) float f32x4;

__device__ __forceinline__ unsigned short f2h(float f) {
    return __builtin_bit_cast(unsigned short, (_Float16)f);  // RNE scalar cvt
}

// f32 pair -> packed f16 (RTZ), one v_cvt_pkrtz_f16_f32
__device__ __forceinline__ f16x2 cvt2(float a, float b) {
    auto r = __builtin_amdgcn_cvt_pkrtz(a, b);
    return __builtin_bit_cast(f16x2, r);
}

// packed ReLU: one v_pk_max_f16 (relu∘cvt == cvt∘relu)
__device__ __forceinline__ f16x2 relu2(f16x2 x) {
    const f16x2 z = {(_Float16)0.f, (_Float16)0.f};
    return __builtin_elementwise_max(x, z);
}

// packed f16 fma: v_pk_fma_f16 (clang generic elementwise builtin, same family
// as elementwise_max which compiled in r8)
__device__ __forceinline__ f16x2 pkfma2(f16x2 a, f16x2 b, f16x2 c) {
    return __builtin_elementwise_fma(a, b, c);
}

// relu + f32->f16 pack: 8 VALU ops per 8 elems
__device__ __forceinline__ f16x8 packR(f32x4 a, f32x4 b) {
    union { f16x2 h[4]; f16x8 v; } o;
    o.h[0] = relu2(cvt2(a[0], a[1]));
    o.h[1] = relu2(cvt2(a[2], a[3]));
    o.h[2] = relu2(cvt2(b[0], b[1]));
    o.h[3] = relu2(cvt2(b[2], b[3]));
    return o.v;
}

// DMA one 16B chunk per lane: global -> LDS (wave-uniform LDS base + lane*16).
__device__ __forceinline__ void gload16(const unsigned short* g, unsigned short* l) {
    __builtin_amdgcn_global_load_lds(
        (const __attribute__((address_space(1))) unsigned int*)g,
        (__attribute__((address_space(3))) unsigned int*)l, 16, 0, 0);
}

// Stage one 16384B slot blob: 4 waves x 4 rounds x 64 lanes x 16B (exact).
__device__ __forceinline__ void stage(unsigned short* lds, const unsigned short* gsrc, int tid) {
    const int lane = tid & 63, wv = tid >> 6;
#pragma unroll
    for (int r = 0; r < 4; ++r) {
        const int chunk = r * 256 + wv * 64;             // in 16B units
        gload16(gsrc + (chunk + lane) * 8, lds + chunk * 8);
    }
}

// One block per (layer, net) slot. A-frag K-permutation
// k(ks,g,e)=16*(2ks+(e>>2))+4g+(e&3) makes layer n's D-layout directly
// consumable as layer n+1's B-operand. Weights stored as f16 bits.
__global__ void prepack_kernel(
    const float* __restrict__ s_w1, const float* __restrict__ s_b1,
    const float* __restrict__ s_w2, const float* __restrict__ s_b2,
    const float* __restrict__ s_w3, const float* __restrict__ s_b3,
    const float* __restrict__ s_w4, const float* __restrict__ s_b4,
    const float* __restrict__ t_w1, const float* __restrict__ t_b1,
    const float* __restrict__ t_w2, const float* __restrict__ t_b2,
    const float* __restrict__ t_w3, const float* __restrict__ t_b3,
    const float* __restrict__ t_w4, const float* __restrict__ t_b4,
    float* __restrict__ ws) {
    const int slot = blockIdx.x;            // l*2 + net
    const int l = slot >> 1, net = slot & 1;
    const int act = l & 1, pass = act ^ 1;
    const float* w1 = (net ? t_w1 : s_w1) + l * HID * 2;
    const float* b1 = (net ? t_b1 : s_b1) + l * HID;
    const float* w2 = (net ? t_w2 : s_w2) + l * HID * HID;
    const float* b2 = (net ? t_b2 : s_b2) + l * HID;
    const float* w3 = (net ? t_w3 : s_w3) + l * HID * HID;
    const float* b3 = (net ? t_b3 : s_b3) + l * HID;
    const float* w4 = (net ? t_w4 : s_w4) + l * 2 * HID;
    const float* b4 = (net ? t_b4 : s_b4) + l * 2;

    unsigned short* wsu = reinterpret_cast<unsigned short*>(ws);
    unsigned short* blob = wsu + slot * SLOT_US;

    // A2 / A3: 64x64 matmul fragments (LDS-staged at runtime)
    for (int mat = 0; mat < 2; ++mat) {
        const float* W = mat ? w3 : w2;
        unsigned short* dst = blob + (mat ? A3_US : A2_US);
        for (int idx = threadIdx.x; idx < 4096; idx += PRE_NTH) {
            const int e = idx & 7, lane = (idx >> 3) & 63, fr = idx >> 9;
            const int ks = fr & 1, mf = fr >> 1;
            const int j = 16 * mf + (lane & 15);
            const int k = 16 * (2 * ks + (e >> 2)) + 4 * (lane >> 4) + (e & 3);
            dst[idx] = f2h(W[j * HID + k]);
        }
    }
    // W1T/B1T: layer-1 per-lane tables in B-frag element order.
    // idx16 = ks*8+e -> hidden unit k = k_phys(ks, g(lane), e).
    for (int idx = threadIdx.x; idx < 1024; idx += PRE_NTH) {
        const int i16 = idx & 15, lane = idx >> 4;
        const int ks = i16 >> 3, e = i16 & 7;
        const int k = 16 * (2 * ks + (e >> 2)) + 4 * (lane >> 4) + (e & 3);
        wsu[W1T_US + (slot * 64 + lane) * 16 + i16] = f2h(w1[2 * k + act]);
        wsu[B1T_US + (slot * 64 + lane) * 16 + i16] = f2h(b1[k]);
    }
    // A4: W4 passive row in A row 0, rows 1..15 zero (global, fragment form)
    for (int idx = threadIdx.x; idx < 1024; idx += PRE_NTH) {
        const int e = idx & 7, lane = (idx >> 3) & 63, ks = idx >> 9;
        const int k = 16 * (2 * ks + (e >> 2)) + 4 * (lane >> 4) + (e & 3);
        wsu[A4_USO + (slot * 128 + ks * 64 + lane) * 8 + e] =
            f2h(((lane & 15) == 0) ? w4[pass * HID + k] : 0.f);
    }
    // biases b2,b3 in D-fragment order (f32)
    float* BP = ws + WS_BIAS_F + slot * 2048;
    for (int which = 0; which < 2; ++which) {
        const float* B = (which == 0) ? b2 : b3;
        for (int idx = threadIdx.x; idx < 1024; idx += PRE_NTH) {
            const int r = idx & 3, lane = (idx >> 2) & 63, f = idx >> 8;
            const int j = 16 * f + 4 * (lane >> 4) + r;
            BP[which * 1024 + idx] = B[j];
        }
    }
    if (threadIdx.x == 0) ws[WS_B4_F + slot] = b4[pass];
}

__global__ __launch_bounds__(NTH) void nvp_mfma_kernel(
    const float* __restrict__ x, const float* __restrict__ ws,
    float* __restrict__ out, int n) {
    __shared__ __align__(16) unsigned short smem[2 * SLOT_US];  // 32 KB double buffer
    const int tid = threadIdx.x;
    const int lane = tid & 63, wv = tid >> 6;
    const int c = lane & 15, g = lane >> 4;
    const int wid = blockIdx.x * (NTH / 64) + wv;
    long base = (long)wid * (16 * SF);
    const bool live = base < n;
    if (!live) base = 0;   // keep barrier participation uniform; skip writes later

    const unsigned short* wsu = reinterpret_cast<const unsigned short*>(ws);

    float y0[SF], y1[SF], ld[SF];
#pragma unroll
    for (int sf = 0; sf < SF; ++sf) {
        const float2 xv = reinterpret_cast<const float2*>(x)[base + 16 * sf + c];
        y0[sf] = xv.x; y1[sf] = xv.y; ld[sf] = 0.f;
    }

    // prologue: stage slot 0
    stage(smem, wsu, tid);

    float sv[SF], tv[SF];
    _Float16 xs[SF];

    for (int slot = 0; slot < 2 * NLAYERS; ++slot) {
        const int net = slot & 1;
        const int act = (slot >> 1) & 1;

        // staged data for this slot is ready after this barrier (vmcnt drained);
        // also closes all waves' reads of the buffer we stage into below.
        __syncthreads();
        if (slot < 2 * NLAYERS - 1)
            stage(smem + ((slot + 1) & 1) * SLOT_US, wsu + (slot + 1) * SLOT_US, tid);

        const unsigned short* SB = smem + (slot & 1) * SLOT_US;
        const float* BP = ws + WS_BIAS_F + slot * 2048;

        if (net == 0) {   // both nets consume the same active input (RNE cast)
#pragma unroll
            for (int sf = 0; sf < SF; ++sf) {
                const float xa = act ? y1[sf] : y0[sf];
                xs[sf] = (_Float16)xa;
            }
        }

        // ---- phase A weights: w1/b1 lane-tables (global), b2 (global), A2 (LDS) ----
        const f16x2* W1L = reinterpret_cast<const f16x2*>(wsu + W1T_US + (slot * 64 + lane) * 16);
        const f16x2* B1L = reinterpret_cast<const f16x2*>(wsu + B1T_US + (slot * 64 + lane) * 16);
        f16x2 w1h[8], b1h[8];
#pragma unroll
        for (int p = 0; p < 8; ++p) { w1h[p] = W1L[p]; b1h[p] = B1L[p]; }
        f16x8 a2[8];
        f32x4 c2v[4];
#pragma unroll
        for (int mf = 0; mf < 4; ++mf)
            c2v[mf] = *reinterpret_cast<const f32x4*>(BP + 0 * 1024 + (mf * 64 + lane) * 4);
#pragma unroll
        for (int fr = 0; fr < 8; ++fr)
            a2[fr] = *reinterpret_cast<const f16x8*>(SB + A2_US + (fr * 64 + lane) * 8);

        f16x8 bfr[SF][2];
#pragma unroll
        for (int sf = 0; sf < SF; ++sf) {
            // layer 1 on packed-f16 VALU: h1 = relu(w1*xa + b1), directly in
            // B-frag element order (single f16 rounding via pk_fma).
            const f16x2 xh2 = {xs[sf], xs[sf]};
            union { f16x2 h[8]; struct { f16x8 lo, hi; } v; } hb;
#pragma unroll
            for (int p = 0; p < 8; ++p)
                hb.h[p] = relu2(pkfma2(w1h[p], xh2, b1h[p]));
            f32x4 acc[4];
            // layer 2: bias as C-in
#pragma unroll
            for (int mf = 0; mf < 4; ++mf) {
                f32x4 t0 = __builtin_amdgcn_mfma_f32_16x16x32_f16(a2[2 * mf + 0], hb.v.lo, c2v[mf], 0, 0, 0);
                acc[mf]  = __builtin_amdgcn_mfma_f32_16x16x32_f16(a2[2 * mf + 1], hb.v.hi, t0, 0, 0, 0);
            }
            bfr[sf][0] = packR(acc[0], acc[1]);
            bfr[sf][1] = packR(acc[2], acc[3]);
        }

        // ---- phase B weights: A3 (LDS), b3 (global), A4 (global), b4 ----
        f16x8 a3[8], a4[2];
        f32x4 c3v[4];
#pragma unroll
        for (int fr = 0; fr < 8; ++fr)
            a3[fr] = *reinterpret_cast<const f16x8*>(SB + A3_US + (fr * 64 + lane) * 8);
#pragma unroll
        for (int mf = 0; mf < 4; ++mf)
            c3v[mf] = *reinterpret_cast<const f32x4*>(BP + 1 * 1024 + (mf * 64 + lane) * 4);
        a4[0] = *reinterpret_cast<const f16x8*>(wsu + A4_USO + (slot * 128 + 0 * 64 + lane) * 8);
        a4[1] = *reinterpret_cast<const f16x8*>(wsu + A4_USO + (slot * 128 + 1 * 64 + lane) * 8);
        const float b4v = ws[WS_B4_F + slot];

#pragma unroll
        for (int sf = 0; sf < SF; ++sf) {
            f32x4 acc[4];
            // layer 3
#pragma unroll
            for (int mf = 0; mf < 4; ++mf) {
                f32x4 t0 = __builtin_amdgcn_mfma_f32_16x16x32_f16(a3[2 * mf + 0], bfr[sf][0], c3v[mf], 0, 0, 0);
                acc[mf]  = __builtin_amdgcn_mfma_f32_16x16x32_f16(a3[2 * mf + 1], bfr[sf][1], t0, 0, 0, 0);
            }
            f16x8 bb0 = packR(acc[0], acc[1]);
            f16x8 bb1 = packR(acc[2], acc[3]);
            // layer 4: W4 row dot via MFMA row 0, then broadcast from lane c
            f32x4 z = {0.f, 0.f, 0.f, 0.f};
            f32x4 d4 = __builtin_amdgcn_mfma_f32_16x16x32_f16(a4[0], bb0, z, 0, 0, 0);
            d4 = __builtin_amdgcn_mfma_f32_16x16x32_f16(a4[1], bb1, d4, 0, 0, 0);
            float p = __builtin_bit_cast(float,
                        __builtin_amdgcn_ds_bpermute(c * 4, __builtin_bit_cast(int, d4[0])));
            p += b4v;
            if (net == 0) sv[sf] = p; else tv[sf] = p;
        }

        if (net == 1) {   // coupling update after both nets done
#pragma unroll
            for (int sf = 0; sf < SF; ++sf) {
                const float e2 = __expf(2.f * sv[sf]);
                const float s = 1.f - 2.f / (e2 + 1.f);      // tanh(sv)
                const float es = __expf(s);
                if (act) y0[sf] = fmaf(y0[sf], es, tv[sf]);
                else     y1[sf] = fmaf(y1[sf], es, tv[sf]);
                ld[sf] += s;
            }
        }
    }

    if (g == 0 && live) {   // 4 lane-groups hold identical results; group 0 writes
#pragma unroll
        for (int sf = 0; sf < SF; ++sf) {
            const long sid = base + 16 * sf + c;
            reinterpret_cast<float2*>(out)[sid] = make_float2(y0[sf], y1[sf]);
            out[2 * (long)n + sid] = ld[sf];
        }
    }
}

extern "C" void kernel_launch(void* const* d_in, const int* in_sizes, int n_in,
                              void* d_out, int out_size, void* d_ws, size_t ws_size,
                              hipStream_t stream) {
    const float* x = (const float*)d_in[0];
    float* ws = (float*)d_ws;

    prepack_kernel<<<16, PRE_NTH, 0, stream>>>(
        (const float*)d_in[1],  (const float*)d_in[2],  (const float*)d_in[3],
        (const float*)d_in[4],  (const float*)d_in[5],  (const float*)d_in[6],
        (const float*)d_in[7],  (const float*)d_in[8],  (const float*)d_in[9],
        (const float*)d_in[10], (const float*)d_in[11], (const float*)d_in[12],
        (const float*)d_in[13], (const float*)d_in[14], (const float*)d_in[15],
        (const float*)d_in[16], ws);

    const int n = in_sizes[0] / 2;                        // x is (N, 2)
    const int samples_per_block = (NTH / 64) * 16 * SF;   // 512
    const int blocks = (n + samples_per_block - 1) / samples_per_block;

    nvp_mfma_kernel<<<blocks, NTH, 0, stream>>>(x, ws, (float*)d_out, n);
}